// Round 5
// baseline (308.574 us; speedup 1.0000x reference)
//
#include <hip/hip_runtime.h>
#include <hip/hip_bf16.h>
#include <cstdint>
#include <cstddef>

typedef __bf16 bf16_t;
typedef bf16_t bf16x8 __attribute__((ext_vector_type(8)));
typedef float f32x4 __attribute__((ext_vector_type(4)));

#define BN_EPS 1e-5f

// r7: per-lane GLOBAL addrs for global_load_lds stay lane-order contiguous;
// LDS swizzles only via pre-swizzled SOURCE addrs.
// r11 (REGRESSED): reg-direct B with DUPLICATED reads across waves = 2x traffic.
// r12/r13: inner-loop schedule variants all ~291-302 us — schedule wasn't it.
// r14 (WIN, 291->174): per-block fusion + 3 blocks/CU. Left-over cost: h1
// global round-trip (128 MB write + ~115 MB HBM re-read; per-XCD L2 can't
// hold 96 blocks x 128 KB).
// r15: FULL fusion — h1 never leaves the CU. Per 256-col chunk: gemm1 ->
// h1c in LDS (32 KB, swizzled) -> gemm2-partial accumulates that K-range
// into persistent acc2 (128 AGPRs/wave, wave owns 128 N-cols; W2T fragments
// reg-direct from L2, DISJOINT per wave — no duplication). Zero barriers
// inside the 256-MFMA gemm2p chunk; 2 barriers per chunk total.
__device__ __forceinline__ void async_load16(const bf16_t* g, bf16_t* lds) {
  __builtin_amdgcn_global_load_lds(
      (__attribute__((address_space(1))) uint32_t*)(g),
      (__attribute__((address_space(3))) uint32_t*)(lds),
      16, 0, 0);
}

// ---- Weight prep (transposes + BN folds), tiny ------------------------------
__global__ void prep_weights_kernel(const float* __restrict__ W1, const float* __restrict__ W2,
                                    const float* b1, const float* g1, const float* be1,
                                    const float* m1, const float* v1,
                                    const float* b2, const float* g2, const float* be2,
                                    const float* m2, const float* v2,
                                    bf16_t* __restrict__ W1T, bf16_t* __restrict__ W2T,
                                    float* s1, float* t1, float* s2, float* t2,
                                    float* w1last) {
  const int b = blockIdx.x;
  if (b < 192) {
    const float* src;
    bf16_t* dst;
    int R, C, bx, by;
    if (b < 64) { src = W1; dst = W1T; R = 256; C = 1024; bx = b & 15; by = b >> 4; }
    else        { src = W2; dst = W2T; R = 1024; C = 512; bx = (b - 64) & 7; by = (b - 64) >> 3; }
    __shared__ bf16_t tile[64][66];
    const int r0 = by * 64, c0 = bx * 64;
    const int tc = threadIdx.x & 63;
    const int tr4 = threadIdx.x >> 6;
#pragma unroll
    for (int i = 0; i < 16; ++i) {
      int r = i * 4 + tr4;
      tile[r][tc] = (bf16_t)src[(size_t)(r0 + r) * C + c0 + tc];  // coalesced read
    }
    __syncthreads();
#pragma unroll
    for (int i = 0; i < 16; ++i) {
      int rr = i * 4 + tr4;
      dst[(size_t)(c0 + rr) * R + r0 + tc] = tile[tc][rr];  // coalesced write
    }
  } else {
    for (int i = threadIdx.x; i < 1024; i += 256) {
      float s = g1[i] * rsqrtf(v1[i] + BN_EPS);
      s1[i] = s;
      t1[i] = be1[i] - m1[i] * s + b1[i] * s;  // bn(z+b1) = z*s + t
      w1last[i] = W1[256 * 1024 + i];          // conv-feature row (coalesced)
      if (i < 512) {
        float s2v = g2[i] * rsqrtf(v2[i] + BN_EPS);
        s2[i] = s2v;
        t2[i] = be2[i] - m2[i] * s2v + b2[i] * s2v;
      }
    }
  }
}

// ---- Fully-fused per-block MLP: 64 rows end-to-end, h1 LDS-only -------------
// LDS 72 KB: As[64][256] bf16 (32 KB, chunk-swizzled) | h1c[64][256] bf16
// (32 KB, chunk-swizzled; convs[64] overlays pre-use) | B1s 4 waves x 2 KB
// (8 KB; outW[256] overlays at the very end).
__global__ __launch_bounds__(256, 2) void fused_mlp(
    const float* __restrict__ x,
    const bf16_t* __restrict__ W1T, const bf16_t* __restrict__ W2T,
    const float* __restrict__ s1, const float* __restrict__ t1,
    const float* __restrict__ w1last,
    const float* __restrict__ s2, const float* __restrict__ t2,
    const float* __restrict__ W3, const float* __restrict__ b3,
    float* __restrict__ out) {
  __shared__ __align__(16) unsigned char smem[73728];
  const int tid = threadIdx.x;
  const int lane = tid & 63;
  const int w = tid >> 6;
  const int l15 = lane & 15;
  const int quad = lane >> 4;
  const int mTile = blockIdx.x * 64;

  bf16_t* As = (bf16_t*)smem;                 // [64][256], chunk-swizzled
  bf16_t* h1c = (bf16_t*)(smem + 32768);      // [64][256], chunk-swizzled
  float* convs = (float*)(smem + 32768);      // overlay (pre-h1c use)
  bf16_t* B1s = (bf16_t*)(smem + 65536);      // [4 waves][32 cols][32 k]
  float* outW = (float*)(smem + 65536);       // overlay (post-B1s use)

  // ---- prologue: x fp32 -> bf16 into As (swizzled), per-row conv ----------
  {
    const int rsub = lane >> 5;     // 0..1
    const int cc = lane & 31;       // 8-elem chunk within row
#pragma unroll
    for (int i = 0; i < 8; ++i) {
      int row = w * 16 + i * 2 + rsub;
      const float* gx = x + (size_t)(mTile + row) * 256 + cc * 8;
      const float4 a = *(const float4*)gx;
      const float4 bq = *(const float4*)(gx + 4);
      float s = a.x + a.y + a.z + a.w + bq.x + bq.y + bq.z + bq.w;
      bf16x8 v = {(bf16_t)a.x, (bf16_t)a.y, (bf16_t)a.z, (bf16_t)a.w,
                  (bf16_t)bq.x, (bf16_t)bq.y, (bf16_t)bq.z, (bf16_t)bq.w};
      *(bf16x8*)(As + row * 256 + (cc ^ (row & 7)) * 8) = v;
#pragma unroll
      for (int m = 1; m <= 16; m <<= 1) s += __shfl_xor(s, m);  // 32-lane groups
      if (cc == 0) convs[row] = (s > 0.0f) ? 1.0f : 0.0f;  // mean>0 <=> sum>0
    }
  }
  __syncthreads();  // As + convs visible

  // Conv feature bitmask over the 16 output rows this lane owns.
  unsigned cmask = 0;
#pragma unroll
  for (int ti = 0; ti < 4; ++ti)
#pragma unroll
    for (int r = 0; r < 4; ++r)
      if (convs[ti * 16 + quad * 4 + r] > 0.5f) cmask |= (1u << (ti * 4 + r));

  bf16_t* B1w = B1s + w * 1024;         // this wave's private 2 KB region
  const int srow = lane >> 2;           // 0..15
  const int schunk = (lane & 3) ^ ((lane >> 3) & 3);   // pre-swizzled src chunk
  const int rchunk = quad ^ ((l15 >> 1) & 3);          // read-side inverse

  // Persistent gemm2 accumulators: wave owns N-cols [w*128, w*128+128).
  f32x4 acc2[4][8];
#pragma unroll
  for (int i = 0; i < 4; ++i)
#pragma unroll
    for (int j = 0; j < 8; ++j) {
      f32x4 z = {0.f, 0.f, 0.f, 0.f};
      acc2[i][j] = z;
    }

  for (int c = 0; c < 4; ++c) {
    // ---- gemm1 for this chunk's 256 cols; wave w owns cols c*256+w*64..+63,
    // processed in two 32-col halves (acc1 = 32 regs live at a time).
#pragma unroll
    for (int h = 0; h < 2; ++h) {
      const int colbase = c * 256 + w * 64 + h * 32;   // absolute W1-col / h1-col
      f32x4 acc1[4][2];
#pragma unroll
      for (int i = 0; i < 4; ++i)
#pragma unroll
        for (int t = 0; t < 2; ++t) {
          f32x4 z = {0.f, 0.f, 0.f, 0.f};
          acc1[i][t] = z;
        }

      const bf16_t* gB1 = W1T + (size_t)(colbase + srow) * 256 + schunk * 8;

#pragma unroll
      for (int i = 0; i < 2; ++i)
        async_load16(gB1 + (size_t)(i * 16) * 256, B1w + i * 512 + lane * 8);

      for (int ks = 0; ks < 8; ++ks) {
        asm volatile("s_waitcnt vmcnt(0)" ::: "memory");  // per-wave stage drain

        bf16x8 af[4], bfr[2];
#pragma unroll
        for (int tj = 0; tj < 2; ++tj)
          bfr[tj] = *(const bf16x8*)(B1w + (tj * 16 + l15) * 32 + rchunk * 8);
#pragma unroll
        for (int ti = 0; ti < 4; ++ti)
          af[ti] = *(const bf16x8*)(As + (ti * 16 + l15) * 256 +
                                    ((ks * 4 + quad) ^ (l15 & 7)) * 8);

        asm volatile("s_waitcnt lgkmcnt(0)" ::: "memory");  // frags in regs
        if (ks < 7) {
#pragma unroll
          for (int i = 0; i < 2; ++i)
            async_load16(gB1 + (size_t)(i * 16) * 256 + (ks + 1) * 32,
                         B1w + i * 512 + lane * 8);
        }

#pragma unroll
        for (int ti = 0; ti < 4; ++ti)
#pragma unroll
          for (int tj = 0; tj < 2; ++tj)
            acc1[ti][tj] = __builtin_amdgcn_mfma_f32_16x16x32_bf16(af[ti], bfr[tj], acc1[ti][tj], 0, 0, 0);
      }

      if (h == 0) __syncthreads();  // WAR: all waves done reading h1c (chunk c-1)

      // Epilogue: conv rank-1 + BN1 + ReLU -> h1c (LDS, swizzled)
      float sc1[2], tc1[2], wl1[2];
#pragma unroll
      for (int tj = 0; tj < 2; ++tj) {
        int ccol = colbase + tj * 16 + l15;
        sc1[tj] = s1[ccol];
        tc1[tj] = t1[ccol];
        wl1[tj] = w1last[ccol];
      }
#pragma unroll
      for (int ti = 0; ti < 4; ++ti)
#pragma unroll
        for (int r = 0; r < 4; ++r) {
          const int rowl = ti * 16 + quad * 4 + r;
          const float cfv = ((cmask >> (ti * 4 + r)) & 1u) ? 1.0f : 0.0f;
#pragma unroll
          for (int tj = 0; tj < 2; ++tj) {
            float z = acc1[ti][tj][r] + cfv * wl1[tj];
            z = fmaxf(z * sc1[tj] + tc1[tj], 0.f);
            const int colc = w * 64 + h * 32 + tj * 16 + l15;  // 0..255 in chunk
            const int c8 = (colc >> 3) ^ (rowl & 7);
            h1c[rowl * 256 + c8 * 8 + (l15 & 7)] = (bf16_t)z;
          }
        }
    }
    __syncthreads();  // h1c chunk complete + visible

    // ---- gemm2 partial: K-range [c*256,(c+1)*256), N = wave's 128 cols.
    // B fragments reg-direct from L2 (disjoint per wave); A from h1c LDS.
    // Zero barriers: compiler free to pipeline all 12 loads/step x 8 steps.
    const bf16_t* gB2 = W2T + (size_t)(w * 128 + l15) * 1024 + c * 256 + quad * 8;
#pragma unroll
    for (int s = 0; s < 8; ++s) {
      bf16x8 af2[4], bfr2[8];
#pragma unroll
      for (int tj = 0; tj < 8; ++tj)
        bfr2[tj] = *(const bf16x8*)(gB2 + (size_t)(tj * 16) * 1024 + s * 32);
#pragma unroll
      for (int ti = 0; ti < 4; ++ti)
        af2[ti] = *(const bf16x8*)(h1c + (ti * 16 + l15) * 256 +
                                   ((s * 4 + quad) ^ (l15 & 7)) * 8);
      __builtin_amdgcn_s_setprio(1);
#pragma unroll
      for (int ti = 0; ti < 4; ++ti)
#pragma unroll
        for (int tj = 0; tj < 8; ++tj)
          acc2[ti][tj] = __builtin_amdgcn_mfma_f32_16x16x32_bf16(af2[ti], bfr2[tj], acc2[ti][tj], 0, 0, 0);
      __builtin_amdgcn_s_setprio(0);
    }
  }

  // ---- final epilogue: BN2 + ReLU + dot W3 over this wave's 128 N-cols ----
  float sc[8], tcs[8], w3c[8];
#pragma unroll
  for (int tj = 0; tj < 8; ++tj) {
    int ccol = w * 128 + tj * 16 + l15;
    sc[tj] = s2[ccol];
    tcs[tj] = t2[ccol];
    w3c[tj] = W3[ccol];
  }
  __syncthreads();  // B1s fully retired before outW overlay
  float rowpv[4][4];
#pragma unroll
  for (int ti = 0; ti < 4; ++ti)
#pragma unroll
    for (int r = 0; r < 4; ++r) {
      float pv = 0.f;
#pragma unroll
      for (int tj = 0; tj < 8; ++tj) {
        float z = fmaxf(acc2[ti][tj][r] * sc[tj] + tcs[tj], 0.f);
        pv += z * w3c[tj];
      }
#pragma unroll
      for (int m = 1; m <= 8; m <<= 1) pv += __shfl_xor(pv, m);
      rowpv[ti][r] = pv;
    }
  if (l15 == 0) {
#pragma unroll
    for (int ti = 0; ti < 4; ++ti)
#pragma unroll
      for (int r = 0; r < 4; ++r)
        outW[w * 64 + ti * 16 + quad * 4 + r] = rowpv[ti][r];
  }
  __syncthreads();
  if (tid < 64) {
    float z = outW[tid] + outW[64 + tid] + outW[128 + tid] + outW[192 + tid] + b3[0];
    out[mTile + tid] = 1.0f / (1.0f + expf(-z));
  }
}

extern "C" void kernel_launch(void* const* d_in, const int* in_sizes, int n_in,
                              void* d_out, int out_size, void* d_ws, size_t ws_size,
                              hipStream_t stream) {
  const float* x = (const float*)d_in[0];
  const float* W1 = (const float*)d_in[1];
  const float* b1 = (const float*)d_in[2];
  const float* g1 = (const float*)d_in[3];
  const float* be1 = (const float*)d_in[4];
  const float* m1 = (const float*)d_in[5];
  const float* v1 = (const float*)d_in[6];
  const float* W2 = (const float*)d_in[7];
  const float* b2 = (const float*)d_in[8];
  const float* g2 = (const float*)d_in[9];
  const float* be2 = (const float*)d_in[10];
  const float* m2 = (const float*)d_in[11];
  const float* v2 = (const float*)d_in[12];
  const float* W3 = (const float*)d_in[13];
  const float* b3 = (const float*)d_in[14];
  float* out = (float*)d_out;

  char* p = (char*)d_ws;
  bf16_t* h1 = (bf16_t*)p;       p += (size_t)65536 * 1024 * 2;  // unused (layout kept)
  float* partials = (float*)p;   p += (size_t)4 * 65536 * 4;     // unused
  bf16_t* W1T = (bf16_t*)p;      p += (size_t)1024 * 256 * 2;
  bf16_t* W2T = (bf16_t*)p;      p += (size_t)512 * 1024 * 2;
  float* w1last = (float*)p;     p += 1024 * 4;
  float* s1 = (float*)p;         p += 1024 * 4;
  float* t1 = (float*)p;         p += 1024 * 4;
  float* s2 = (float*)p;         p += 512 * 4;
  float* t2 = (float*)p;         p += 512 * 4;
  (void)h1;
  (void)partials;

  prep_weights_kernel<<<193, 256, 0, stream>>>(W1, W2, b1, g1, be1, m1, v1,
                                               b2, g2, be2, m2, v2,
                                               W1T, W2T, s1, t1, s2, t2, w1last);

  fused_mlp<<<1024, 256, 0, stream>>>(x, W1T, W2T, s1, t1, w1last,
                                      s2, t2, W3, b3, out);
}